// Round 1
// baseline (1156.386 us; speedup 1.0000x reference)
//
#include <hip/hip_runtime.h>
#include <math.h>

// Problem constants
#define B_   32
#define T0_  256
#define J_   512
#define V_   1024
#define Q_   32
#define L_   20
#define P_   241
#define NEG_ (-1e9f)

// ---------------------------------------------------------------------------
// FC: v[b][j][t] = sum_v video[b][t][v] * fc_w[j][v] + fc_b[j]
// GEMM M=8192 (b,t), N=512 (j), K=1024. Output stored transposed [B][J][T].
// ---------------------------------------------------------------------------
__global__ __launch_bounds__(256) void fc_kernel(
    const float* __restrict__ A, const float* __restrict__ Bw,
    const float* __restrict__ bias, float* __restrict__ out) {
  __shared__ float As[32][65];  // [k][m]
  __shared__ float Bs[32][65];  // [k][n]
  int m0 = blockIdx.x * 64, n0 = blockIdx.y * 64;
  int tid = threadIdx.x;
  int tm = (tid & 15) * 4, tn = (tid >> 4) * 4;
  float acc[4][4] = {};
  for (int k0 = 0; k0 < 1024; k0 += 32) {
    #pragma unroll
    for (int i = 0; i < 2; ++i) {
      int idx = tid + i * 256;          // 0..511 float4 slots
      int r = idx >> 3;                 // row 0..63
      int c = (idx & 7) * 4;            // col 0..28
      float4 v = *reinterpret_cast<const float4*>(&A[(size_t)(m0 + r) * 1024 + k0 + c]);
      As[c + 0][r] = v.x; As[c + 1][r] = v.y; As[c + 2][r] = v.z; As[c + 3][r] = v.w;
      float4 w = *reinterpret_cast<const float4*>(&Bw[(size_t)(n0 + r) * 1024 + k0 + c]);
      Bs[c + 0][r] = w.x; Bs[c + 1][r] = w.y; Bs[c + 2][r] = w.z; Bs[c + 3][r] = w.w;
    }
    __syncthreads();
    #pragma unroll
    for (int kk = 0; kk < 32; ++kk) {
      float a[4], b[4];
      #pragma unroll
      for (int i = 0; i < 4; ++i) a[i] = As[kk][tm + i];
      #pragma unroll
      for (int i = 0; i < 4; ++i) b[i] = Bs[kk][tn + i];
      #pragma unroll
      for (int i = 0; i < 4; ++i)
        #pragma unroll
        for (int j = 0; j < 4; ++j) acc[i][j] += a[i] * b[j];
    }
    __syncthreads();
  }
  #pragma unroll
  for (int i = 0; i < 4; ++i) {
    int m = m0 + tm + i; int b = m >> 8; int t = m & 255;
    #pragma unroll
    for (int j = 0; j < 4; ++j) {
      int jj = n0 + tn + j;
      out[((size_t)b * J_ + jj) * T0_ + t] = acc[i][j] + bias[jj];
    }
  }
}

// ---------------------------------------------------------------------------
// Conv1d layer: out[b][o][t] = relu( sum_{i,k} in[b][i][2t+k]*w[o][i][k] + cb[o] )
// Tile: 64 out-ch x 32 t. Reduction over 512 in-ch in chunks of 16.
// ---------------------------------------------------------------------------
__global__ __launch_bounds__(256) void conv_kernel(
    const float* __restrict__ in, const float* __restrict__ w,
    const float* __restrict__ cb, float* __restrict__ out,
    int Tin, int Tout) {
  __shared__ float ws_[64][68];   // [o][i*4+k], padded (8 row-groups -> distinct banks)
  __shared__ float xs[16][68];    // [i][input pos]
  int b = blockIdx.x;
  int o0 = blockIdx.y * 64;
  int t0 = blockIdx.z * 32;
  int tid = threadIdx.x;
  int tt = (tid & 7) * 4;       // t offset 0..28
  int oo = (tid >> 3) * 2;      // o offset 0..62
  float acc[2][4] = {};
  const float* inb = in + (size_t)b * J_ * Tin;
  for (int i0 = 0; i0 < J_; i0 += 16) {
    #pragma unroll
    for (int ld = 0; ld < 4; ++ld) {
      int idx = tid + ld * 256;        // 1024 float4 slots
      int o = idx >> 4;                // 0..63
      int c = (idx & 15) * 4;          // 0..60
      float4 vv = *reinterpret_cast<const float4*>(
          &w[((size_t)(o0 + o) * J_ + i0) * 4 + c]);
      *reinterpret_cast<float4*>(&ws_[o][c]) = vv;
    }
    for (int idx = tid; idx < 16 * 66; idx += 256) {
      int i = idx / 66, c = idx % 66;
      int tin = 2 * t0 + c;
      xs[i][c] = (tin < Tin) ? inb[(size_t)(i0 + i) * Tin + tin] : 0.f;
    }
    __syncthreads();
    #pragma unroll
    for (int i = 0; i < 16; ++i) {
      float xv[10];
      #pragma unroll
      for (int c = 0; c < 10; ++c) xv[c] = xs[i][2 * tt + c];
      float w0[4], w1[4];
      #pragma unroll
      for (int k = 0; k < 4; ++k) { w0[k] = ws_[oo][i * 4 + k]; w1[k] = ws_[oo + 1][i * 4 + k]; }
      #pragma unroll
      for (int t = 0; t < 4; ++t)
        #pragma unroll
        for (int k = 0; k < 4; ++k) {
          acc[0][t] += w0[k] * xv[2 * t + k];
          acc[1][t] += w1[k] * xv[2 * t + k];
        }
    }
    __syncthreads();
  }
  #pragma unroll
  for (int oi = 0; oi < 2; ++oi) {
    int o = o0 + oo + oi;
    float bias = cb[o];
    #pragma unroll
    for (int t_ = 0; t_ < 4; ++t_) {
      int t = t0 + tt + t_;
      if (t < Tout) {
        float v = acc[oi][t_] + bias;
        out[((size_t)b * J_ + o) * Tout + t] = fmaxf(v, 0.f);
      }
    }
  }
}

// ---------------------------------------------------------------------------
// Pointwise 1x1 conv: f_all[b][Poff+t][o] = sum_i v[b][i][t]*pw[o][i] + pb[o]
// ---------------------------------------------------------------------------
__global__ __launch_bounds__(256) void pw_kernel(
    const float* __restrict__ v, const float* __restrict__ pwt,
    const float* __restrict__ pb, float* __restrict__ f_all,
    int Tl, int Poff) {
  __shared__ float ps[64][36];  // [o][ii]
  __shared__ float vs[32][33];  // [ii][t]
  int b = blockIdx.x, o0 = blockIdx.y * 64, t0 = blockIdx.z * 32;
  int tid = threadIdx.x;
  int tt = (tid & 7) * 4, oo = (tid >> 3) * 2;
  float acc[2][4] = {};
  const float* vb = v + (size_t)b * J_ * Tl;
  for (int i0 = 0; i0 < J_; i0 += 32) {
    #pragma unroll
    for (int ld = 0; ld < 2; ++ld) {
      int idx = tid + ld * 256;       // 512 float4 slots
      int o = idx >> 3, c = (idx & 7) * 4;
      float4 vv = *reinterpret_cast<const float4*>(&pwt[(size_t)(o0 + o) * J_ + i0 + c]);
      *reinterpret_cast<float4*>(&ps[o][c]) = vv;
    }
    for (int idx = tid; idx < 32 * 32; idx += 256) {
      int ii = idx >> 5, c = idx & 31;
      int t = t0 + c;
      vs[ii][c] = (t < Tl) ? vb[(size_t)(i0 + ii) * Tl + t] : 0.f;
    }
    __syncthreads();
    #pragma unroll
    for (int ii = 0; ii < 32; ++ii) {
      float a[4];
      #pragma unroll
      for (int t = 0; t < 4; ++t) a[t] = vs[ii][tt + t];
      float w0 = ps[oo][ii], w1 = ps[oo + 1][ii];
      #pragma unroll
      for (int t = 0; t < 4; ++t) { acc[0][t] += w0 * a[t]; acc[1][t] += w1 * a[t]; }
    }
    __syncthreads();
  }
  #pragma unroll
  for (int oi = 0; oi < 2; ++oi) {
    int o = o0 + oo + oi;
    float bias = pb[o];
    #pragma unroll
    for (int t_ = 0; t_ < 4; ++t_) {
      int t = t0 + tt + t_;
      if (t < Tl) f_all[((size_t)b * P_ + Poff + t) * J_ + o] = acc[oi][t_] + bias;
    }
  }
}

// ---------------------------------------------------------------------------
// Row L2 norms of f_all: one wave per row of 512.
// ---------------------------------------------------------------------------
__global__ __launch_bounds__(256) void fnorm_kernel(
    const float* __restrict__ f, float* __restrict__ fn) {
  int gw = (blockIdx.x * 256 + threadIdx.x) >> 6;
  int lane = threadIdx.x & 63;
  if (gw >= B_ * P_) return;
  const float* row = f + (size_t)gw * J_;
  float s = 0.f;
  #pragma unroll
  for (int i = 0; i < 8; ++i) { float x = row[lane + 64 * i]; s += x * x; }
  #pragma unroll
  for (int off = 32; off; off >>= 1) s += __shfl_xor(s, off);
  if (lane == 0) fn[gw] = sqrtf(s);
}

// ---------------------------------------------------------------------------
// Per-query word Gram matrices: G[q][l][l2] = dot512(words[q,l], words[q,l2])
// ---------------------------------------------------------------------------
__global__ __launch_bounds__(256) void gram_kernel(
    const float* __restrict__ words, float* __restrict__ gram) {
  __shared__ float wsh[L_][513];
  int q = blockIdx.x, tid = threadIdx.x;
  for (int idx = tid; idx < L_ * 512; idx += 256)
    wsh[idx >> 9][idx & 511] = words[(size_t)q * L_ * J_ + idx];
  __syncthreads();
  for (int pr = tid; pr < L_ * L_; pr += 256) {
    int l = pr / L_, l2 = pr % L_;
    float sum = 0.f;
    for (int d = 0; d < J_; ++d) sum += wsh[l][d] * wsh[l2][d];
    gram[q * L_ * L_ + pr] = sum;
  }
}

// ---------------------------------------------------------------------------
// Attention logits: C[m][n] = dot512(f_all[m], words_flat[n]); M=7712, N=640
// ---------------------------------------------------------------------------
__global__ __launch_bounds__(256) void logits_kernel(
    const float* __restrict__ A, const float* __restrict__ W,
    float* __restrict__ C) {
  __shared__ float As[32][65];
  __shared__ float Bs[32][65];
  int m0 = blockIdx.x * 64, n0 = blockIdx.y * 64;
  int tid = threadIdx.x;
  int tm = (tid & 15) * 4, tn = (tid >> 4) * 4;
  float acc[4][4] = {};
  for (int k0 = 0; k0 < 512; k0 += 32) {
    #pragma unroll
    for (int i = 0; i < 2; ++i) {
      int idx = tid + i * 256;
      int r = idx >> 3;
      int c = (idx & 7) * 4;
      int m = m0 + r;
      float4 v;
      if (m < B_ * P_) v = *reinterpret_cast<const float4*>(&A[(size_t)m * J_ + k0 + c]);
      else { v.x = v.y = v.z = v.w = 0.f; }
      As[c + 0][r] = v.x; As[c + 1][r] = v.y; As[c + 2][r] = v.z; As[c + 3][r] = v.w;
      float4 w = *reinterpret_cast<const float4*>(&W[(size_t)(n0 + r) * J_ + k0 + c]);
      Bs[c + 0][r] = w.x; Bs[c + 1][r] = w.y; Bs[c + 2][r] = w.z; Bs[c + 3][r] = w.w;
    }
    __syncthreads();
    #pragma unroll
    for (int kk = 0; kk < 32; ++kk) {
      float a[4], b[4];
      #pragma unroll
      for (int i = 0; i < 4; ++i) a[i] = As[kk][tm + i];
      #pragma unroll
      for (int i = 0; i < 4; ++i) b[i] = Bs[kk][tn + i];
      #pragma unroll
      for (int i = 0; i < 4; ++i)
        #pragma unroll
        for (int j = 0; j < 4; ++j) acc[i][j] += a[i] * b[j];
    }
    __syncthreads();
  }
  #pragma unroll
  for (int i = 0; i < 4; ++i) {
    int m = m0 + tm + i;
    if (m < B_ * P_) {
      #pragma unroll
      for (int j = 0; j < 4; ++j) C[(size_t)m * (Q_ * L_) + n0 + tn + j] = acc[i][j];
    }
  }
}

// ---------------------------------------------------------------------------
// Softmax + cosine-sim epilogue per (q,b,p).
// sim = (sum_l att_l*logit_l) / ((|f|+eps)*(sqrt(att^T G att)+eps))
// ---------------------------------------------------------------------------
__global__ __launch_bounds__(256) void sim_kernel(
    const float* __restrict__ logits, const float* __restrict__ gram,
    const float* __restrict__ fnorm, float* __restrict__ score) {
  int idx = blockIdx.x * 256 + threadIdx.x;
  if (idx >= Q_ * B_ * P_) return;
  int q = idx / (B_ * P_);
  int r = idx - q * (B_ * P_);
  const float* lg = &logits[(size_t)r * (Q_ * L_) + q * L_];
  float raw[L_], e[L_];
  float m = -1e30f;
  #pragma unroll
  for (int l = 0; l < L_; ++l) { raw[l] = lg[l]; m = fmaxf(m, raw[l]); }
  float s = 0.f;
  #pragma unroll
  for (int l = 0; l < L_; ++l) { e[l] = __expf(raw[l] - m); s += e[l]; }
  float inv = 1.f / s;
  float fvs = 0.f;
  #pragma unroll
  for (int l = 0; l < L_; ++l) fvs += e[l] * raw[l];
  fvs *= inv;
  const float* G = &gram[q * L_ * L_];
  float vn2 = 0.f;
  for (int l = 0; l < L_; ++l) {
    float acc = 0.f;
    #pragma unroll
    for (int l2 = 0; l2 < L_; ++l2) acc += e[l2] * G[l * L_ + l2];
    vn2 += e[l] * acc;
  }
  vn2 *= inv * inv;
  float fn = fnorm[r] + 1e-8f;
  float vn = sqrtf(fmaxf(vn2, 0.f)) + 1e-8f;
  score[idx] = fvs / (fn * vn);
}

// ---------------------------------------------------------------------------
// Greedy NMS: one wave per (q,b) row of 241 scores, 5 picks.
// ---------------------------------------------------------------------------
__global__ __launch_bounds__(256) void nms_kernel(
    const float* __restrict__ score, const float* __restrict__ iou,
    const float* __restrict__ lam, float* __restrict__ smat) {
  int wid = (blockIdx.x * 256 + threadIdx.x) >> 6;
  int lane = threadIdx.x & 63;
  if (wid >= Q_ * B_) return;
  const float* srow = &score[(size_t)wid * P_];
  float s[4];
  #pragma unroll
  for (int i = 0; i < 4; ++i) {
    int p = lane + 64 * i;
    s[i] = (p < P_) ? srow[p] : NEG_;
  }
  float lamv = lam[0];
  float acc = 0.f, wgt = 1.f;
  for (int k = 0; k < 5; ++k) {
    float bv = NEG_ * 2.f; int bi = 1 << 30;
    #pragma unroll
    for (int i = 0; i < 4; ++i) {
      int p = lane + 64 * i;
      if (s[i] > bv) { bv = s[i]; bi = p; }
    }
    for (int off = 32; off; off >>= 1) {
      float ov = __shfl_xor(bv, off);
      int oi = __shfl_xor(bi, off);
      if (ov > bv || (ov == bv && oi < bi)) { bv = ov; bi = oi; }
    }
    acc += bv * wgt;
    wgt *= lamv;
    const float* irow = &iou[(size_t)bi * P_];
    #pragma unroll
    for (int i = 0; i < 4; ++i) {
      int p = lane + 64 * i;
      if (p < P_ && irow[p] > 0.7f) s[i] = NEG_;
      if (p == bi) s[i] = NEG_;
    }
  }
  if (lane == 0) smat[wid] = acc * 0.2f;   // /NMS_K
}

// ---------------------------------------------------------------------------
// positive_map: out[1 + b*P + p] = score[b][b][p]
// ---------------------------------------------------------------------------
__global__ __launch_bounds__(256) void posmap_kernel(
    const float* __restrict__ score, float* __restrict__ out) {
  int idx = blockIdx.x * 256 + threadIdx.x;
  if (idx >= B_ * P_) return;
  int b = idx / P_, p = idx - b * P_;
  out[1 + idx] = score[((size_t)(b * B_ + b)) * P_ + p];
}

// ---------------------------------------------------------------------------
// diag margin loss over scores_mat [32][32] -> out[0]
// ---------------------------------------------------------------------------
__global__ __launch_bounds__(1024) void loss_kernel(
    const float* __restrict__ smat, float* __restrict__ out) {
  __shared__ float sm[B_][B_ + 1];
  __shared__ float red[16];
  int tid = threadIdx.x;
  sm[tid >> 5][tid & 31] = smat[tid];
  __syncthreads();
  int i = tid >> 5, j = tid & 31;
  float val = 0.f;
  if (i != j) {
    float sij = sm[i][j];
    val = fmaxf(0.f, 0.2f + sij - sm[i][i]) + fmaxf(0.f, 0.2f + sij - sm[j][j]);
  }
  #pragma unroll
  for (int off = 32; off; off >>= 1) val += __shfl_xor(val, off);
  if ((tid & 63) == 0) red[tid >> 6] = val;
  __syncthreads();
  if (tid == 0) {
    float t = 0.f;
    #pragma unroll
    for (int w = 0; w < 16; ++w) t += red[w];
    out[0] = t / 32.f;
  }
}

extern "C" void kernel_launch(void* const* d_in, const int* in_sizes, int n_in,
                              void* d_out, int out_size, void* d_ws, size_t ws_size,
                              hipStream_t stream) {
  const float* video  = (const float*)d_in[0];
  const float* words  = (const float*)d_in[1];
  // d_in[2] = w_masks: all-ones by construction, unused
  const float* lam    = (const float*)d_in[3];
  const float* iou    = (const float*)d_in[4];
  const float* fc_w   = (const float*)d_in[5];
  const float* fc_b   = (const float*)d_in[6];
  const float* conv_w = (const float*)d_in[7];
  const float* conv_b = (const float*)d_in[8];
  const float* pw     = (const float*)d_in[9];
  const float* pb     = (const float*)d_in[10];
  float* out = (float*)d_out;

  float* ws     = (float*)d_ws;
  float* v_a    = ws;                       // 4,194,304 (B*J*256)
  float* v_b    = v_a + 4194304;            // 2,097,152 (B*J*128)
  float* f_all  = v_b + 2097152;            // 3,952,640 (B*P*J)
  float* fnorm  = f_all + 3952640;          // 7,936
  float* gram   = fnorm + 7936;             // 12,800
  float* logits = gram + 12800;             // 4,935,680 (B*P * Q*L)
  float* score  = logits + 4935680;         // 246,784 (Q*B*P)
  float* smat   = score + 246784;           // 1,024

  // 1) FC projection
  fc_kernel<<<dim3(128, 8), 256, 0, stream>>>(video, fc_w, fc_b, v_a);

  // 2) conv pyramid + pointwise projections
  const int Tl[6]   = {127, 62, 30, 14, 6, 2};
  const int Tin[6]  = {256, 127, 62, 30, 14, 6};
  const int Poff[6] = {0, 127, 189, 219, 233, 239};
  float* cur = v_a;
  float* nxt = v_b;
  for (int li = 0; li < 6; ++li) {
    int tt = (Tl[li] + 31) / 32;
    conv_kernel<<<dim3(B_, 8, tt), 256, 0, stream>>>(
        cur, conv_w + (size_t)li * J_ * J_ * 4, conv_b + li * J_, nxt, Tin[li], Tl[li]);
    pw_kernel<<<dim3(B_, 8, tt), 256, 0, stream>>>(nxt, pw, pb, f_all, Tl[li], Poff[li]);
    float* tmp = cur; cur = nxt; nxt = tmp;
  }

  // 3) norms, Gram, attention logits
  fnorm_kernel<<<(B_ * P_) / 4, 256, 0, stream>>>(f_all, fnorm);
  gram_kernel<<<Q_, 256, 0, stream>>>(words, gram);
  logits_kernel<<<dim3((B_ * P_ + 63) / 64, 10), 256, 0, stream>>>(f_all, words, logits);

  // 4) softmax + cosine similarity
  sim_kernel<<<(Q_ * B_ * P_ + 255) / 256, 256, 0, stream>>>(logits, gram, fnorm, score);

  // 5) NMS, positive_map, loss
  nms_kernel<<<(Q_ * B_ * 64 + 255) / 256, 256, 0, stream>>>(score, iou, lam, smat);
  posmap_kernel<<<(B_ * P_ + 255) / 256, 256, 0, stream>>>(score, out);
  loss_kernel<<<1, 1024, 0, stream>>>(smat, out);
}

// Round 2
// 975.449 us; speedup vs baseline: 1.1855x; 1.1855x over previous
//
#include <hip/hip_runtime.h>
#include <math.h>

// Problem constants
#define B_   32
#define T0_  256
#define J_   512
#define V_   1024
#define Q_   32
#define L_   20
#define P_   241
#define NEG_ (-1e9f)

typedef __attribute__((ext_vector_type(8))) short short8;
typedef __attribute__((ext_vector_type(4))) float f32x4;

__device__ __forceinline__ unsigned short f2bf_rne(float x) {
  unsigned u = __float_as_uint(x);
  unsigned r = u + 0x7fffu + ((u >> 16) & 1u);
  return (unsigned short)(r >> 16);
}

// ---------------------------------------------------------------------------
// Split-bf16 MFMA GEMM: C[m][n] = sum_k A[m][k]*B[n][k]  (both row-major, K
// contiguous). 128x128 block tile, 4 waves (2x2), 64x64 wave tile of 4x4
// mfma_f32_16x16x32_bf16 tiles. 3-pass split: Ahi*Bhi + Alo*Bhi + Ahi*Blo.
// EPI 0: fc epilogue  -> out[b][n][t] = C + bias[n]   (m = b*256+t)
// EPI 1: plain        -> out[m][NCOLS] = C            (guard m < MROWS)
// ---------------------------------------------------------------------------
template<int KTOT, int MROWS, int NCOLS, int EPI>
__global__ __launch_bounds__(256) void mfma_gemm(
    const float* __restrict__ A, const float* __restrict__ Bm,
    const float* __restrict__ bias, float* __restrict__ out) {
  constexpr bool MG = (MROWS % 128) != 0;
  constexpr int NI = KTOT / 32;
  // 4 planes: 0=A_hi, 1=A_lo, 2=B_hi, 3=B_lo. Row stride 40 shorts (80B):
  // stride 20 words, gcd(20,32)=4, b128 reads -> uniform 8 accesses/bank.
  __shared__ short lds_s[4][128 * 40];

  const int tid = threadIdx.x;
  const int m0 = blockIdx.x * 128, n0 = blockIdx.y * 128;
  const int wave = tid >> 6, lane = tid & 63;
  const int wm = (wave >> 1) * 64, wn = (wave & 1) * 64;
  const int fr = lane & 15, fq = lane >> 4;

  // staging assignment: row 0..127, k-half 0..1 (16 f32 each)
  const int srow = tid >> 1, kh = tid & 1;

  f32x4 acc[4][4];
  #pragma unroll
  for (int i = 0; i < 4; ++i)
    #pragma unroll
    for (int j = 0; j < 4; ++j) acc[i][j] = (f32x4)0.f;

  float4 ra[4], rb[4];

  auto loadA = [&](int it) {
    int gm = m0 + srow;
    const float* p = A + (size_t)gm * KTOT + it * 32 + kh * 16;
    if (!MG || gm < MROWS) {
      #pragma unroll
      for (int i = 0; i < 4; ++i) ra[i] = *reinterpret_cast<const float4*>(p + 4 * i);
    } else {
      #pragma unroll
      for (int i = 0; i < 4; ++i) ra[i] = make_float4(0.f, 0.f, 0.f, 0.f);
    }
  };
  auto loadB = [&](int it) {
    const float* p = Bm + (size_t)(n0 + srow) * KTOT + it * 32 + kh * 16;
    #pragma unroll
    for (int i = 0; i < 4; ++i) rb[i] = *reinterpret_cast<const float4*>(p + 4 * i);
  };

  auto stage = [&](const float4 r[4], short* hip, short* lop) {
    float tf[16];
    #pragma unroll
    for (int i = 0; i < 4; ++i) *reinterpret_cast<float4*>(&tf[4 * i]) = r[i];
    const int base = srow * 40 + kh * 16;
    #pragma unroll
    for (int g = 0; g < 2; ++g) {
      short8 h8, l8;
      #pragma unroll
      for (int j = 0; j < 8; ++j) {
        float x = tf[g * 8 + j];
        unsigned short h = f2bf_rne(x);
        float hf = __uint_as_float((unsigned)h << 16);
        h8[j] = (short)h;
        l8[j] = (short)f2bf_rne(x - hf);
      }
      *reinterpret_cast<short8*>(&hip[base + g * 8]) = h8;
      *reinterpret_cast<short8*>(&lop[base + g * 8]) = l8;
    }
  };

  const int abase = (wm + fr) * 40 + fq * 8;
  const int bbase = (wn + fr) * 40 + fq * 8;

  loadA(0); loadB(0);
  for (int it = 0; it < NI; ++it) {
    __syncthreads();                  // previous compute done reading LDS
    stage(ra, lds_s[0], lds_s[1]);
    stage(rb, lds_s[2], lds_s[3]);
    __syncthreads();
    if (it + 1 < NI) { loadA(it + 1); loadB(it + 1); }  // hide under compute

    short8 a[4], b[4], a2[4];
    #pragma unroll
    for (int mt = 0; mt < 4; ++mt)
      a[mt] = *reinterpret_cast<const short8*>(&lds_s[0][abase + mt * 640]);
    #pragma unroll
    for (int nt = 0; nt < 4; ++nt)
      b[nt] = *reinterpret_cast<const short8*>(&lds_s[2][bbase + nt * 640]);
    #pragma unroll
    for (int mt = 0; mt < 4; ++mt)
      #pragma unroll
      for (int nt = 0; nt < 4; ++nt)
        acc[mt][nt] = __builtin_amdgcn_mfma_f32_16x16x32_bf16(a[mt], b[nt], acc[mt][nt], 0, 0, 0);
    #pragma unroll
    for (int mt = 0; mt < 4; ++mt)
      a2[mt] = *reinterpret_cast<const short8*>(&lds_s[1][abase + mt * 640]);
    #pragma unroll
    for (int mt = 0; mt < 4; ++mt)
      #pragma unroll
      for (int nt = 0; nt < 4; ++nt)
        acc[mt][nt] = __builtin_amdgcn_mfma_f32_16x16x32_bf16(a2[mt], b[nt], acc[mt][nt], 0, 0, 0);
    #pragma unroll
    for (int nt = 0; nt < 4; ++nt)
      b[nt] = *reinterpret_cast<const short8*>(&lds_s[3][bbase + nt * 640]);
    #pragma unroll
    for (int mt = 0; mt < 4; ++mt)
      #pragma unroll
      for (int nt = 0; nt < 4; ++nt)
        acc[mt][nt] = __builtin_amdgcn_mfma_f32_16x16x32_bf16(a[mt], b[nt], acc[mt][nt], 0, 0, 0);
  }

  // Epilogue. C layout: col = lane&15 (n), row = fq*4 + reg (m).
  #pragma unroll
  for (int mt = 0; mt < 4; ++mt) {
    int mBase = m0 + wm + mt * 16 + fq * 4;
    #pragma unroll
    for (int nt = 0; nt < 4; ++nt) {
      int n = n0 + wn + nt * 16 + fr;
      f32x4 c = acc[mt][nt];
      if (EPI == 0) {
        float bv = bias[n];
        int b = mBase >> 8, t = mBase & 255;
        float4 o = make_float4(c.x + bv, c.y + bv, c.z + bv, c.w + bv);
        *reinterpret_cast<float4*>(&out[((size_t)b * NCOLS + n) * T0_ + t]) = o;
      } else {
        #pragma unroll
        for (int r = 0; r < 4; ++r) {
          int m = mBase + r;
          if (!MG || m < MROWS) out[(size_t)m * NCOLS + n] = c[r];
        }
      }
    }
  }
}

// ---------------------------------------------------------------------------
// Conv1d layer: out[b][o][t] = relu( sum_{i,k} in[b][i][2t+k]*w[o][i][k] + cb[o] )
// ---------------------------------------------------------------------------
__global__ __launch_bounds__(256) void conv_kernel(
    const float* __restrict__ in, const float* __restrict__ w,
    const float* __restrict__ cb, float* __restrict__ out,
    int Tin, int Tout) {
  __shared__ float ws_[64][68];
  __shared__ float xs[16][68];
  int b = blockIdx.x;
  int o0 = blockIdx.y * 64;
  int t0 = blockIdx.z * 32;
  int tid = threadIdx.x;
  int tt = (tid & 7) * 4;
  int oo = (tid >> 3) * 2;
  float acc[2][4] = {};
  const float* inb = in + (size_t)b * J_ * Tin;
  for (int i0 = 0; i0 < J_; i0 += 16) {
    #pragma unroll
    for (int ld = 0; ld < 4; ++ld) {
      int idx = tid + ld * 256;
      int o = idx >> 4;
      int c = (idx & 15) * 4;
      float4 vv = *reinterpret_cast<const float4*>(
          &w[((size_t)(o0 + o) * J_ + i0) * 4 + c]);
      *reinterpret_cast<float4*>(&ws_[o][c]) = vv;
    }
    for (int idx = tid; idx < 16 * 66; idx += 256) {
      int i = idx / 66, c = idx % 66;
      int tin = 2 * t0 + c;
      xs[i][c] = (tin < Tin) ? inb[(size_t)(i0 + i) * Tin + tin] : 0.f;
    }
    __syncthreads();
    #pragma unroll
    for (int i = 0; i < 16; ++i) {
      float xv[10];
      #pragma unroll
      for (int c = 0; c < 10; ++c) xv[c] = xs[i][2 * tt + c];
      float w0[4], w1[4];
      #pragma unroll
      for (int k = 0; k < 4; ++k) { w0[k] = ws_[oo][i * 4 + k]; w1[k] = ws_[oo + 1][i * 4 + k]; }
      #pragma unroll
      for (int t = 0; t < 4; ++t)
        #pragma unroll
        for (int k = 0; k < 4; ++k) {
          acc[0][t] += w0[k] * xv[2 * t + k];
          acc[1][t] += w1[k] * xv[2 * t + k];
        }
    }
    __syncthreads();
  }
  #pragma unroll
  for (int oi = 0; oi < 2; ++oi) {
    int o = o0 + oo + oi;
    float bias = cb[o];
    #pragma unroll
    for (int t_ = 0; t_ < 4; ++t_) {
      int t = t0 + tt + t_;
      if (t < Tout) {
        float v = acc[oi][t_] + bias;
        out[((size_t)b * J_ + o) * Tout + t] = fmaxf(v, 0.f);
      }
    }
  }
}

// ---------------------------------------------------------------------------
// Pointwise 1x1 conv: f_all[b][Poff+t][o] = sum_i v[b][i][t]*pw[o][i] + pb[o]
// ---------------------------------------------------------------------------
__global__ __launch_bounds__(256) void pw_kernel(
    const float* __restrict__ v, const float* __restrict__ pwt,
    const float* __restrict__ pb, float* __restrict__ f_all,
    int Tl, int Poff) {
  __shared__ float ps[64][36];
  __shared__ float vs[32][33];
  int b = blockIdx.x, o0 = blockIdx.y * 64, t0 = blockIdx.z * 32;
  int tid = threadIdx.x;
  int tt = (tid & 7) * 4, oo = (tid >> 3) * 2;
  float acc[2][4] = {};
  const float* vb = v + (size_t)b * J_ * Tl;
  for (int i0 = 0; i0 < J_; i0 += 32) {
    #pragma unroll
    for (int ld = 0; ld < 2; ++ld) {
      int idx = tid + ld * 256;
      int o = idx >> 3, c = (idx & 7) * 4;
      float4 vv = *reinterpret_cast<const float4*>(&pwt[(size_t)(o0 + o) * J_ + i0 + c]);
      *reinterpret_cast<float4*>(&ps[o][c]) = vv;
    }
    for (int idx = tid; idx < 32 * 32; idx += 256) {
      int ii = idx >> 5, c = idx & 31;
      int t = t0 + c;
      vs[ii][c] = (t < Tl) ? vb[(size_t)(i0 + ii) * Tl + t] : 0.f;
    }
    __syncthreads();
    #pragma unroll
    for (int ii = 0; ii < 32; ++ii) {
      float a[4];
      #pragma unroll
      for (int t = 0; t < 4; ++t) a[t] = vs[ii][tt + t];
      float w0 = ps[oo][ii], w1 = ps[oo + 1][ii];
      #pragma unroll
      for (int t = 0; t < 4; ++t) { acc[0][t] += w0 * a[t]; acc[1][t] += w1 * a[t]; }
    }
    __syncthreads();
  }
  #pragma unroll
  for (int oi = 0; oi < 2; ++oi) {
    int o = o0 + oo + oi;
    float bias = pb[o];
    #pragma unroll
    for (int t_ = 0; t_ < 4; ++t_) {
      int t = t0 + tt + t_;
      if (t < Tl) f_all[((size_t)b * P_ + Poff + t) * J_ + o] = acc[oi][t_] + bias;
    }
  }
}

// ---------------------------------------------------------------------------
// Row L2 norms of f_all
// ---------------------------------------------------------------------------
__global__ __launch_bounds__(256) void fnorm_kernel(
    const float* __restrict__ f, float* __restrict__ fn) {
  int gw = (blockIdx.x * 256 + threadIdx.x) >> 6;
  int lane = threadIdx.x & 63;
  if (gw >= B_ * P_) return;
  const float* row = f + (size_t)gw * J_;
  float s = 0.f;
  #pragma unroll
  for (int i = 0; i < 8; ++i) { float x = row[lane + 64 * i]; s += x * x; }
  #pragma unroll
  for (int off = 32; off; off >>= 1) s += __shfl_xor(s, off);
  if (lane == 0) fn[gw] = sqrtf(s);
}

// ---------------------------------------------------------------------------
// Per-query word Gram matrices
// ---------------------------------------------------------------------------
__global__ __launch_bounds__(256) void gram_kernel(
    const float* __restrict__ words, float* __restrict__ gram) {
  __shared__ float wsh[L_][513];
  int q = blockIdx.x, tid = threadIdx.x;
  for (int idx = tid; idx < L_ * 512; idx += 256)
    wsh[idx >> 9][idx & 511] = words[(size_t)q * L_ * J_ + idx];
  __syncthreads();
  for (int pr = tid; pr < L_ * L_; pr += 256) {
    int l = pr / L_, l2 = pr % L_;
    float sum = 0.f;
    for (int d = 0; d < J_; ++d) sum += wsh[l][d] * wsh[l2][d];
    gram[q * L_ * L_ + pr] = sum;
  }
}

// ---------------------------------------------------------------------------
// Softmax + cosine-sim epilogue per (q,b,p).
// ---------------------------------------------------------------------------
__global__ __launch_bounds__(256) void sim_kernel(
    const float* __restrict__ logits, const float* __restrict__ gram,
    const float* __restrict__ fnorm, float* __restrict__ score) {
  int idx = blockIdx.x * 256 + threadIdx.x;
  if (idx >= Q_ * B_ * P_) return;
  int q = idx / (B_ * P_);
  int r = idx - q * (B_ * P_);
  const float* lg = &logits[(size_t)r * (Q_ * L_) + q * L_];
  float raw[L_], e[L_];
  float m = -1e30f;
  #pragma unroll
  for (int l = 0; l < L_; ++l) { raw[l] = lg[l]; m = fmaxf(m, raw[l]); }
  float s = 0.f;
  #pragma unroll
  for (int l = 0; l < L_; ++l) { e[l] = __expf(raw[l] - m); s += e[l]; }
  float inv = 1.f / s;
  float fvs = 0.f;
  #pragma unroll
  for (int l = 0; l < L_; ++l) fvs += e[l] * raw[l];
  fvs *= inv;
  const float* G = &gram[q * L_ * L_];
  float vn2 = 0.f;
  for (int l = 0; l < L_; ++l) {
    float acc = 0.f;
    #pragma unroll
    for (int l2 = 0; l2 < L_; ++l2) acc += e[l2] * G[l * L_ + l2];
    vn2 += e[l] * acc;
  }
  vn2 *= inv * inv;
  float fn = fnorm[r] + 1e-8f;
  float vn = sqrtf(fmaxf(vn2, 0.f)) + 1e-8f;
  score[idx] = fvs / (fn * vn);
}

// ---------------------------------------------------------------------------
// Greedy NMS
// ---------------------------------------------------------------------------
__global__ __launch_bounds__(256) void nms_kernel(
    const float* __restrict__ score, const float* __restrict__ iou,
    const float* __restrict__ lam, float* __restrict__ smat) {
  int wid = (blockIdx.x * 256 + threadIdx.x) >> 6;
  int lane = threadIdx.x & 63;
  if (wid >= Q_ * B_) return;
  const float* srow = &score[(size_t)wid * P_];
  float s[4];
  #pragma unroll
  for (int i = 0; i < 4; ++i) {
    int p = lane + 64 * i;
    s[i] = (p < P_) ? srow[p] : NEG_;
  }
  float lamv = lam[0];
  float acc = 0.f, wgt = 1.f;
  for (int k = 0; k < 5; ++k) {
    float bv = NEG_ * 2.f; int bi = 1 << 30;
    #pragma unroll
    for (int i = 0; i < 4; ++i) {
      int p = lane + 64 * i;
      if (s[i] > bv) { bv = s[i]; bi = p; }
    }
    for (int off = 32; off; off >>= 1) {
      float ov = __shfl_xor(bv, off);
      int oi = __shfl_xor(bi, off);
      if (ov > bv || (ov == bv && oi < bi)) { bv = ov; bi = oi; }
    }
    acc += bv * wgt;
    wgt *= lamv;
    const float* irow = &iou[(size_t)bi * P_];
    #pragma unroll
    for (int i = 0; i < 4; ++i) {
      int p = lane + 64 * i;
      if (p < P_ && irow[p] > 0.7f) s[i] = NEG_;
      if (p == bi) s[i] = NEG_;
    }
  }
  if (lane == 0) smat[wid] = acc * 0.2f;
}

// ---------------------------------------------------------------------------
// positive_map
// ---------------------------------------------------------------------------
__global__ __launch_bounds__(256) void posmap_kernel(
    const float* __restrict__ score, float* __restrict__ out) {
  int idx = blockIdx.x * 256 + threadIdx.x;
  if (idx >= B_ * P_) return;
  int b = idx / P_, p = idx - b * P_;
  out[1 + idx] = score[((size_t)(b * B_ + b)) * P_ + p];
}

// ---------------------------------------------------------------------------
// diag margin loss
// ---------------------------------------------------------------------------
__global__ __launch_bounds__(1024) void loss_kernel(
    const float* __restrict__ smat, float* __restrict__ out) {
  __shared__ float sm[B_][B_ + 1];
  __shared__ float red[16];
  int tid = threadIdx.x;
  sm[tid >> 5][tid & 31] = smat[tid];
  __syncthreads();
  int i = tid >> 5, j = tid & 31;
  float val = 0.f;
  if (i != j) {
    float sij = sm[i][j];
    val = fmaxf(0.f, 0.2f + sij - sm[i][i]) + fmaxf(0.f, 0.2f + sij - sm[j][j]);
  }
  #pragma unroll
  for (int off = 32; off; off >>= 1) val += __shfl_xor(val, off);
  if ((tid & 63) == 0) red[tid >> 6] = val;
  __syncthreads();
  if (tid == 0) {
    float t = 0.f;
    #pragma unroll
    for (int w = 0; w < 16; ++w) t += red[w];
    out[0] = t / 32.f;
  }
}

extern "C" void kernel_launch(void* const* d_in, const int* in_sizes, int n_in,
                              void* d_out, int out_size, void* d_ws, size_t ws_size,
                              hipStream_t stream) {
  const float* video  = (const float*)d_in[0];
  const float* words  = (const float*)d_in[1];
  // d_in[2] = w_masks: all-ones by construction, unused
  const float* lam    = (const float*)d_in[3];
  const float* iou    = (const float*)d_in[4];
  const float* fc_w   = (const float*)d_in[5];
  const float* fc_b   = (const float*)d_in[6];
  const float* conv_w = (const float*)d_in[7];
  const float* conv_b = (const float*)d_in[8];
  const float* pw     = (const float*)d_in[9];
  const float* pb     = (const float*)d_in[10];
  float* out = (float*)d_out;

  float* ws     = (float*)d_ws;
  float* v_a    = ws;                       // B*J*256
  float* v_b    = v_a + 4194304;            // B*J*128
  float* f_all  = v_b + 2097152;            // B*P*J
  float* fnorm  = f_all + 3952640;
  float* gram   = fnorm + 7936;
  float* logits = gram + 12800;             // B*P * Q*L
  float* score  = logits + 4935680;
  float* smat   = score + 246784;

  // 1) FC projection: split-bf16 MFMA GEMM, M=8192 N=512 K=1024
  mfma_gemm<1024, 8192, 512, 0><<<dim3(64, 4), 256, 0, stream>>>(video, fc_w, fc_b, v_a);

  // 2) conv pyramid + pointwise projections (vector, unchanged)
  const int Tl[6]   = {127, 62, 30, 14, 6, 2};
  const int Tin[6]  = {256, 127, 62, 30, 14, 6};
  const int Poff[6] = {0, 127, 189, 219, 233, 239};
  float* cur = v_a;
  float* nxt = v_b;
  for (int li = 0; li < 6; ++li) {
    int tt = (Tl[li] + 31) / 32;
    conv_kernel<<<dim3(B_, 8, tt), 256, 0, stream>>>(
        cur, conv_w + (size_t)li * J_ * J_ * 4, conv_b + li * J_, nxt, Tin[li], Tl[li]);
    pw_kernel<<<dim3(B_, 8, tt), 256, 0, stream>>>(nxt, pw, pb, f_all, Tl[li], Poff[li]);
    float* tmp = cur; cur = nxt; nxt = tmp;
  }

  // 3) norms, Gram, attention logits (logits: split-bf16 MFMA GEMM)
  fnorm_kernel<<<(B_ * P_) / 4, 256, 0, stream>>>(f_all, fnorm);
  gram_kernel<<<Q_, 256, 0, stream>>>(words, gram);
  mfma_gemm<512, 7712, 640, 1><<<dim3(61, 5), 256, 0, stream>>>(f_all, words, nullptr, logits);

  // 4) softmax + cosine similarity
  sim_kernel<<<(Q_ * B_ * P_ + 255) / 256, 256, 0, stream>>>(logits, gram, fnorm, score);

  // 5) NMS, positive_map, loss
  nms_kernel<<<(Q_ * B_ * 64 + 255) / 256, 256, 0, stream>>>(score, iou, lam, smat);
  posmap_kernel<<<(B_ * P_ + 255) / 256, 256, 0, stream>>>(score, out);
  loss_kernel<<<1, 1024, 0, stream>>>(smat, out);
}

// Round 3
// 665.464 us; speedup vs baseline: 1.7377x; 1.4658x over previous
//
#include <hip/hip_runtime.h>
#include <math.h>

// Problem constants
#define B_   32
#define T0_  256
#define J_   512
#define V_   1024
#define Q_   32
#define L_   20
#define P_   241
#define NEG_ (-1e9f)

typedef __attribute__((ext_vector_type(8))) short short8;
typedef __attribute__((ext_vector_type(4))) float f32x4;

__device__ __forceinline__ unsigned short f2bf_rne(float x) {
  unsigned u = __float_as_uint(x);
  unsigned r = u + 0x7fffu + ((u >> 16) & 1u);
  return (unsigned short)(r >> 16);
}

// ---------------------------------------------------------------------------
// Generalized split-bf16 MFMA GEMM over a row-mapped A view.
//   C[m][n] = sum_k Aview[m][k] * Bm[n][k]
//   Aview row m starts at A + arow(m)*ASTRIDE, arow = (m/TDIV)*SB + S0 + (m%TDIV)*TMUL
//   (im2col for stride-2 K=4 conv is TMUL=2, ASTRIDE=512, KTOT=2048 — the
//    4 input rows 2t..2t+3 are contiguous in [B][T][J] layout.)
//   Out row: orow = (m/TDIV)*OSB + OS0 + (m%TDIV); out[orow*NS + n].
// 128x128 block tile, 4 waves (2x2), 64x64 wave tile, mfma_f32_16x16x32_bf16.
// 3-pass split: Ahi*Bhi + Alo*Bhi + Ahi*Blo.
// EPI: 0 = +bias, 1 = +bias+relu, 2 = plain
// ---------------------------------------------------------------------------
template<int KTOT, int EPI>
__global__ __launch_bounds__(256) void mfma_gemm(
    const float* __restrict__ A, const float* __restrict__ Bm,
    const float* __restrict__ bias, float* __restrict__ out,
    int MROWS, int TDIV, int SB, int S0, int TMUL, int ASTRIDE,
    int OSB, int OS0, int NS) {
  constexpr int NI = KTOT / 32;
  // 4 planes: 0=A_hi, 1=A_lo, 2=B_hi, 3=B_lo. Row stride 40 shorts (80B):
  // stride 20 words, gcd(20,32)=4, b128 reads -> uniform 8 accesses/bank.
  __shared__ short lds_s[4][128 * 40];

  const int tid = threadIdx.x;
  const int m0 = blockIdx.x * 128, n0 = blockIdx.y * 128;
  const int wave = tid >> 6, lane = tid & 63;
  const int wm = (wave >> 1) * 64, wn = (wave & 1) * 64;
  const int fr = lane & 15, fq = lane >> 4;

  // staging assignment: row 0..127, k-half 0..1 (16 f32 each)
  const int srow = tid >> 1, kh = tid & 1;

  // A-view row offset for this thread's staging row (constant across k-iters)
  const int gm = m0 + srow;
  const bool mval = gm < MROWS;
  int bb = gm / TDIV, tt_ = gm - bb * TDIV;
  const size_t aoff = (size_t)(bb * SB + S0 + tt_ * TMUL) * (size_t)ASTRIDE;

  f32x4 acc[4][4];
  #pragma unroll
  for (int i = 0; i < 4; ++i)
    #pragma unroll
    for (int j = 0; j < 4; ++j) acc[i][j] = (f32x4)0.f;

  float4 ra[4], rb[4];

  auto loadA = [&](int it) {
    if (mval) {
      const float* p = A + aoff + it * 32 + kh * 16;
      #pragma unroll
      for (int i = 0; i < 4; ++i) ra[i] = *reinterpret_cast<const float4*>(p + 4 * i);
    } else {
      #pragma unroll
      for (int i = 0; i < 4; ++i) ra[i] = make_float4(0.f, 0.f, 0.f, 0.f);
    }
  };
  auto loadB = [&](int it) {
    const float* p = Bm + (size_t)(n0 + srow) * KTOT + it * 32 + kh * 16;
    #pragma unroll
    for (int i = 0; i < 4; ++i) rb[i] = *reinterpret_cast<const float4*>(p + 4 * i);
  };

  auto stage = [&](const float4 r[4], short* hip, short* lop) {
    float tf[16];
    #pragma unroll
    for (int i = 0; i < 4; ++i) *reinterpret_cast<float4*>(&tf[4 * i]) = r[i];
    const int base = srow * 40 + kh * 16;
    #pragma unroll
    for (int g = 0; g < 2; ++g) {
      short8 h8, l8;
      #pragma unroll
      for (int j = 0; j < 8; ++j) {
        float x = tf[g * 8 + j];
        unsigned short h = f2bf_rne(x);
        float hf = __uint_as_float((unsigned)h << 16);
        h8[j] = (short)h;
        l8[j] = (short)f2bf_rne(x - hf);
      }
      *reinterpret_cast<short8*>(&hip[base + g * 8]) = h8;
      *reinterpret_cast<short8*>(&lop[base + g * 8]) = l8;
    }
  };

  const int abase = (wm + fr) * 40 + fq * 8;
  const int bbase = (wn + fr) * 40 + fq * 8;

  loadA(0); loadB(0);
  for (int it = 0; it < NI; ++it) {
    __syncthreads();                  // previous compute done reading LDS
    stage(ra, lds_s[0], lds_s[1]);
    stage(rb, lds_s[2], lds_s[3]);
    __syncthreads();
    if (it + 1 < NI) { loadA(it + 1); loadB(it + 1); }  // hide under compute

    short8 a[4], b[4], a2[4];
    #pragma unroll
    for (int mt = 0; mt < 4; ++mt)
      a[mt] = *reinterpret_cast<const short8*>(&lds_s[0][abase + mt * 640]);
    #pragma unroll
    for (int nt = 0; nt < 4; ++nt)
      b[nt] = *reinterpret_cast<const short8*>(&lds_s[2][bbase + nt * 640]);
    #pragma unroll
    for (int mt = 0; mt < 4; ++mt)
      #pragma unroll
      for (int nt = 0; nt < 4; ++nt)
        acc[mt][nt] = __builtin_amdgcn_mfma_f32_16x16x32_bf16(a[mt], b[nt], acc[mt][nt], 0, 0, 0);
    #pragma unroll
    for (int mt = 0; mt < 4; ++mt)
      a2[mt] = *reinterpret_cast<const short8*>(&lds_s[1][abase + mt * 640]);
    #pragma unroll
    for (int mt = 0; mt < 4; ++mt)
      #pragma unroll
      for (int nt = 0; nt < 4; ++nt)
        acc[mt][nt] = __builtin_amdgcn_mfma_f32_16x16x32_bf16(a2[mt], b[nt], acc[mt][nt], 0, 0, 0);
    #pragma unroll
    for (int nt = 0; nt < 4; ++nt)
      b[nt] = *reinterpret_cast<const short8*>(&lds_s[3][bbase + nt * 640]);
    #pragma unroll
    for (int mt = 0; mt < 4; ++mt)
      #pragma unroll
      for (int nt = 0; nt < 4; ++nt)
        acc[mt][nt] = __builtin_amdgcn_mfma_f32_16x16x32_bf16(a[mt], b[nt], acc[mt][nt], 0, 0, 0);
  }

  // Epilogue. C layout: col = lane&15 (n), row = fq*4 + reg (m).
  #pragma unroll
  for (int mt = 0; mt < 4; ++mt) {
    int mBase = m0 + wm + mt * 16 + fq * 4;
    #pragma unroll
    for (int nt = 0; nt < 4; ++nt) {
      int n = n0 + wn + nt * 16 + fr;
      float bv = (EPI == 2) ? 0.f : bias[n];
      f32x4 c = acc[mt][nt];
      #pragma unroll
      for (int r = 0; r < 4; ++r) {
        int m = mBase + r;
        if (m < MROWS) {
          int b2 = m / TDIV, t2 = m - b2 * TDIV;
          int orow = b2 * OSB + OS0 + t2;
          float v = c[r] + bv;
          if (EPI == 1) v = fmaxf(v, 0.f);
          out[(size_t)orow * NS + n] = v;
        }
      }
    }
  }
}

// ---------------------------------------------------------------------------
// Repack conv weights: wr[li][o][k*512+i] = conv_w[li][o][i][k]
// ---------------------------------------------------------------------------
__global__ __launch_bounds__(256) void repack_kernel(
    const float* __restrict__ w, float* __restrict__ wr) {
  int e = blockIdx.x * 256 + threadIdx.x;   // (li,o,i) triple
  if (e >= 6 * 512 * 512) return;
  int li = e >> 18;
  int rem = e & 262143;
  int o = rem >> 9;
  int i = rem & 511;
  float4 v = *reinterpret_cast<const float4*>(&w[(size_t)e * 4]);
  float* dst = &wr[((size_t)(li * 512 + o)) * 2048 + i];
  dst[0]    = v.x;
  dst[512]  = v.y;
  dst[1024] = v.z;
  dst[1536] = v.w;
}

// ---------------------------------------------------------------------------
// Row L2 norms of f_all
// ---------------------------------------------------------------------------
__global__ __launch_bounds__(256) void fnorm_kernel(
    const float* __restrict__ f, float* __restrict__ fn) {
  int gw = (blockIdx.x * 256 + threadIdx.x) >> 6;
  int lane = threadIdx.x & 63;
  if (gw >= B_ * P_) return;
  const float* row = f + (size_t)gw * J_;
  float s = 0.f;
  #pragma unroll
  for (int i = 0; i < 8; ++i) { float x = row[lane + 64 * i]; s += x * x; }
  #pragma unroll
  for (int off = 32; off; off >>= 1) s += __shfl_xor(s, off);
  if (lane == 0) fn[gw] = sqrtf(s);
}

// ---------------------------------------------------------------------------
// Per-query word Gram matrices
// ---------------------------------------------------------------------------
__global__ __launch_bounds__(256) void gram_kernel(
    const float* __restrict__ words, float* __restrict__ gram) {
  __shared__ float wsh[L_][513];
  int q = blockIdx.x, tid = threadIdx.x;
  for (int idx = tid; idx < L_ * 512; idx += 256)
    wsh[idx >> 9][idx & 511] = words[(size_t)q * L_ * J_ + idx];
  __syncthreads();
  for (int pr = tid; pr < L_ * L_; pr += 256) {
    int l = pr / L_, l2 = pr % L_;
    float sum = 0.f;
    for (int d = 0; d < J_; ++d) sum += wsh[l][d] * wsh[l2][d];
    gram[q * L_ * L_ + pr] = sum;
  }
}

// ---------------------------------------------------------------------------
// Softmax + cosine-sim epilogue per (q,b,p).
// sim = (sum_l att_l*logit_l) / ((|f|+eps)*(sqrt(att^T G att)+eps))
// ---------------------------------------------------------------------------
__global__ __launch_bounds__(256) void sim_kernel(
    const float* __restrict__ logits, const float* __restrict__ gram,
    const float* __restrict__ fnorm, float* __restrict__ score) {
  int idx = blockIdx.x * 256 + threadIdx.x;
  if (idx >= Q_ * B_ * P_) return;
  int q = idx / (B_ * P_);
  int r = idx - q * (B_ * P_);
  const float* lg = &logits[(size_t)r * (Q_ * L_) + q * L_];
  float raw[L_], e[L_];
  float m = -1e30f;
  #pragma unroll
  for (int l = 0; l < L_; ++l) { raw[l] = lg[l]; m = fmaxf(m, raw[l]); }
  float s = 0.f;
  #pragma unroll
  for (int l = 0; l < L_; ++l) { e[l] = __expf(raw[l] - m); s += e[l]; }
  float inv = 1.f / s;
  float fvs = 0.f;
  #pragma unroll
  for (int l = 0; l < L_; ++l) fvs += e[l] * raw[l];
  fvs *= inv;
  const float* G = &gram[q * L_ * L_];
  float vn2 = 0.f;
  for (int l = 0; l < L_; ++l) {
    float acc = 0.f;
    #pragma unroll
    for (int l2 = 0; l2 < L_; ++l2) acc += e[l2] * G[l * L_ + l2];
    vn2 += e[l] * acc;
  }
  vn2 *= inv * inv;
  float fn = fnorm[r] + 1e-8f;
  float vn = sqrtf(fmaxf(vn2, 0.f)) + 1e-8f;
  score[idx] = fvs / (fn * vn);
}

// ---------------------------------------------------------------------------
// Greedy NMS
// ---------------------------------------------------------------------------
__global__ __launch_bounds__(256) void nms_kernel(
    const float* __restrict__ score, const float* __restrict__ iou,
    const float* __restrict__ lam, float* __restrict__ smat) {
  int wid = (blockIdx.x * 256 + threadIdx.x) >> 6;
  int lane = threadIdx.x & 63;
  if (wid >= Q_ * B_) return;
  const float* srow = &score[(size_t)wid * P_];
  float s[4];
  #pragma unroll
  for (int i = 0; i < 4; ++i) {
    int p = lane + 64 * i;
    s[i] = (p < P_) ? srow[p] : NEG_;
  }
  float lamv = lam[0];
  float acc = 0.f, wgt = 1.f;
  for (int k = 0; k < 5; ++k) {
    float bv = NEG_ * 2.f; int bi = 1 << 30;
    #pragma unroll
    for (int i = 0; i < 4; ++i) {
      int p = lane + 64 * i;
      if (s[i] > bv) { bv = s[i]; bi = p; }
    }
    for (int off = 32; off; off >>= 1) {
      float ov = __shfl_xor(bv, off);
      int oi = __shfl_xor(bi, off);
      if (ov > bv || (ov == bv && oi < bi)) { bv = ov; bi = oi; }
    }
    acc += bv * wgt;
    wgt *= lamv;
    const float* irow = &iou[(size_t)bi * P_];
    #pragma unroll
    for (int i = 0; i < 4; ++i) {
      int p = lane + 64 * i;
      if (p < P_ && irow[p] > 0.7f) s[i] = NEG_;
      if (p == bi) s[i] = NEG_;
    }
  }
  if (lane == 0) smat[wid] = acc * 0.2f;
}

// ---------------------------------------------------------------------------
// positive_map
// ---------------------------------------------------------------------------
__global__ __launch_bounds__(256) void posmap_kernel(
    const float* __restrict__ score, float* __restrict__ out) {
  int idx = blockIdx.x * 256 + threadIdx.x;
  if (idx >= B_ * P_) return;
  int b = idx / P_, p = idx - b * P_;
  out[1 + idx] = score[((size_t)(b * B_ + b)) * P_ + p];
}

// ---------------------------------------------------------------------------
// diag margin loss
// ---------------------------------------------------------------------------
__global__ __launch_bounds__(1024) void loss_kernel(
    const float* __restrict__ smat, float* __restrict__ out) {
  __shared__ float sm[B_][B_ + 1];
  __shared__ float red[16];
  int tid = threadIdx.x;
  sm[tid >> 5][tid & 31] = smat[tid];
  __syncthreads();
  int i = tid >> 5, j = tid & 31;
  float val = 0.f;
  if (i != j) {
    float sij = sm[i][j];
    val = fmaxf(0.f, 0.2f + sij - sm[i][i]) + fmaxf(0.f, 0.2f + sij - sm[j][j]);
  }
  #pragma unroll
  for (int off = 32; off; off >>= 1) val += __shfl_xor(val, off);
  if ((tid & 63) == 0) red[tid >> 6] = val;
  __syncthreads();
  if (tid == 0) {
    float t = 0.f;
    #pragma unroll
    for (int w = 0; w < 16; ++w) t += red[w];
    out[0] = t / 32.f;
  }
}

extern "C" void kernel_launch(void* const* d_in, const int* in_sizes, int n_in,
                              void* d_out, int out_size, void* d_ws, size_t ws_size,
                              hipStream_t stream) {
  const float* video  = (const float*)d_in[0];
  const float* words  = (const float*)d_in[1];
  // d_in[2] = w_masks: all-ones by construction, unused
  const float* lam    = (const float*)d_in[3];
  const float* iou    = (const float*)d_in[4];
  const float* fc_w   = (const float*)d_in[5];
  const float* fc_b   = (const float*)d_in[6];
  const float* conv_w = (const float*)d_in[7];
  const float* conv_b = (const float*)d_in[8];
  const float* pw     = (const float*)d_in[9];
  const float* pb     = (const float*)d_in[10];
  float* out = (float*)d_out;

  // Workspace layout (floats). Aliases exploit stream-order lifetimes:
  //   f_all  aliases fc_out (fc_out dead after conv0)
  //   logits aliases wr     (wr dead after last conv)
  float* ws     = (float*)d_ws;
  float* fc_out = ws;                       // 4,194,304  [8192][512]
  float* f_all  = fc_out;                   //   alias: 3,948,544 [7712][512]
  float* pyr    = fc_out + 4194304;         // 3,948,544  [B*P][512] (relu'd conv outs)
  float* wr     = pyr + 3948544;            // 6,291,456  repacked conv weights
  float* logits = wr;                       //   alias: 4,935,680 [7712][640]
  float* score  = wr + 6291456;             // 246,784
  float* fnorm  = score + 246784;           // 7,712 (pad 7,936)
  float* gram   = fnorm + 7936;             // 12,800
  float* smat   = gram + 12800;             // 1,024

  const int Tl[6]   = {127, 62, 30, 14, 6, 2};
  const int Poff[6] = {0, 127, 189, 219, 233, 239};

  // 0) repack conv weights to [o][k*512+i] (im2col-compatible K ordering)
  repack_kernel<<<6144, 256, 0, stream>>>(conv_w, wr);

  // 1) FC: M=8192 N=512 K=1024, row-major out + bias
  mfma_gemm<1024, 0><<<dim3(64, 4), 256, 0, stream>>>(
      video, fc_w, fc_b, fc_out,
      8192, 8192, 0, 0, 1, 1024, 0, 0, 512);

  // 2) conv pyramid: each layer one GEMM M=B*Tl, N=512, K=2048 (im2col view)
  for (int li = 0; li < 6; ++li) {
    int M = B_ * Tl[li];
    int mb = (M + 127) / 128;
    const float* inA = (li == 0) ? fc_out : pyr;
    int SB = (li == 0) ? T0_ : P_;
    int S0 = (li == 0) ? 0 : Poff[li - 1];
    mfma_gemm<2048, 1><<<dim3(mb, 4), 256, 0, stream>>>(
        inA, wr + (size_t)li * 512 * 2048, conv_b + li * 512, pyr,
        M, Tl[li], SB, S0, 2, 512, P_, Poff[li], 512);
  }

  // 3) pointwise projection, ALL layers in one GEMM: M=7712, N=512, K=512
  mfma_gemm<512, 0><<<dim3(61, 4), 256, 0, stream>>>(
      pyr, pw, pb, f_all,
      B_ * P_, B_ * P_, 0, 0, 1, 512, 0, 0, 512);

  // 4) norms, Gram, attention logits (M=7712, N=640, K=512)
  fnorm_kernel<<<(B_ * P_) / 4, 256, 0, stream>>>(f_all, fnorm);
  gram_kernel<<<Q_, 256, 0, stream>>>(words, gram);
  mfma_gemm<512, 2><<<dim3(61, 5), 256, 0, stream>>>(
      f_all, words, nullptr, logits,
      B_ * P_, B_ * P_, 0, 0, 1, 512, 0, 0, 640);

  // 5) softmax + cosine similarity
  sim_kernel<<<(Q_ * B_ * P_ + 255) / 256, 256, 0, stream>>>(logits, gram, fnorm, score);

  // 6) NMS, positive_map, loss
  nms_kernel<<<(Q_ * B_ * 64 + 255) / 256, 256, 0, stream>>>(score, iou, lam, smat);
  posmap_kernel<<<(B_ * P_ + 255) / 256, 256, 0, stream>>>(score, out);
  loss_kernel<<<1, 1024, 0, stream>>>(smat, out);
}

// Round 4
// 289.432 us; speedup vs baseline: 3.9954x; 2.2992x over previous
//
#include <hip/hip_runtime.h>
#include <math.h>

// Problem constants
#define B_   32
#define T0_  256
#define J_   512
#define V_   1024
#define Q_   32
#define L_   20
#define P_   241
#define NEG_ (-1e9f)

typedef __attribute__((ext_vector_type(8))) short short8;
typedef __attribute__((ext_vector_type(4))) short short4v;
typedef __attribute__((ext_vector_type(4))) float f32x4;

__device__ __forceinline__ unsigned short f2bf_rne(float x) {
  unsigned u = __float_as_uint(x);
  unsigned r = u + 0x7fffu + ((u >> 16) & 1u);
  return (unsigned short)(r >> 16);
}
__device__ __forceinline__ float bf2f(short v) {
  return __uint_as_float(((unsigned)(unsigned short)v) << 16);
}

// ---------------------------------------------------------------------------
// Split-plane bf16 MFMA GEMM, 64x64 tile, 4 waves (2x2), wave tile 32x32,
// KCH=64 per iter. Operands pre-split into hi/lo bf16 planes (row stride:
// A fixed 512, B = BSTR). 3-pass: Ahi*Bhi + Alo*Bhi + Ahi*Blo.
// A row view: arow = (m/TDIV)*SB + S0 + (m%TDIV)*TMUL  (im2col for conv).
// blockIdx.z = split-K slice (k in [z*KLEN, (z+1)*KLEN)).
// EPI: 0 = +bias -> hi/lo planes; 1 = +bias+relu -> hi/lo planes (orow map);
//      2 = plain f32 out (stride NS); 3 = f32 partials [z][MP][512].
// LDS row stride 72 shorts = 144 B (16B-aligned b128s, uniform 8 acc/bank).
// ---------------------------------------------------------------------------
template<int EPI>
__global__ __launch_bounds__(256) void gemm_bf(
    const short* __restrict__ AH, const short* __restrict__ AL,
    const short* __restrict__ BH, const short* __restrict__ BL,
    const float* __restrict__ bias,
    short* __restrict__ outH, short* __restrict__ outL,
    float* __restrict__ outF,
    int MROWS, int TDIV, int SB, int S0, int TMUL,
    int BSTR, int KLEN, int MP, int OSB, int OS0, int NS) {
  __shared__ short aHs[64 * 72], aLs[64 * 72], bHs[64 * 72], bLs[64 * 72];
  const int tid = threadIdx.x;
  const int m0 = blockIdx.x * 64, n0 = blockIdx.y * 64;
  const int koff0 = blockIdx.z * KLEN;
  const int wave = tid >> 6, lane = tid & 63;
  const int wm = (wave >> 1) * 32, wn = (wave & 1) * 32;
  const int fr = lane & 15, fq = lane >> 4;
  const int srow = tid >> 2, seg = tid & 3;
  const int gm = m0 + srow;
  const bool mval = gm < MROWS;
  const int b2 = gm / TDIV, t2 = gm - b2 * TDIV;
  const size_t aoff = (size_t)(b2 * SB + S0 + t2 * TMUL) * 512;
  const size_t boff = (size_t)(n0 + srow) * (size_t)BSTR;

  f32x4 acc[2][2];
  #pragma unroll
  for (int i = 0; i < 2; ++i)
    #pragma unroll
    for (int j = 0; j < 2; ++j) acc[i][j] = (f32x4)0.f;

  short8 rAH[2], rAL[2], rBH[2], rBL[2];
  auto load = [&](int it) {
    const int k = koff0 + it * 64 + seg * 16;
    if (mval) {
      rAH[0] = *reinterpret_cast<const short8*>(&AH[aoff + k]);
      rAH[1] = *reinterpret_cast<const short8*>(&AH[aoff + k + 8]);
      rAL[0] = *reinterpret_cast<const short8*>(&AL[aoff + k]);
      rAL[1] = *reinterpret_cast<const short8*>(&AL[aoff + k + 8]);
    } else {
      rAH[0] = rAH[1] = rAL[0] = rAL[1] = (short8)0;
    }
    rBH[0] = *reinterpret_cast<const short8*>(&BH[boff + k]);
    rBH[1] = *reinterpret_cast<const short8*>(&BH[boff + k + 8]);
    rBL[0] = *reinterpret_cast<const short8*>(&BL[boff + k]);
    rBL[1] = *reinterpret_cast<const short8*>(&BL[boff + k + 8]);
  };

  load(0);
  const int NI = KLEN / 64;
  const int sb = srow * 72 + seg * 16;
  const int ab = (wm + fr) * 72 + fq * 8;
  const int bb = (wn + fr) * 72 + fq * 8;

  for (int it = 0; it < NI; ++it) {
    __syncthreads();
    *reinterpret_cast<short8*>(&aHs[sb]) = rAH[0];
    *reinterpret_cast<short8*>(&aHs[sb + 8]) = rAH[1];
    *reinterpret_cast<short8*>(&aLs[sb]) = rAL[0];
    *reinterpret_cast<short8*>(&aLs[sb + 8]) = rAL[1];
    *reinterpret_cast<short8*>(&bHs[sb]) = rBH[0];
    *reinterpret_cast<short8*>(&bHs[sb + 8]) = rBH[1];
    *reinterpret_cast<short8*>(&bLs[sb]) = rBL[0];
    *reinterpret_cast<short8*>(&bLs[sb + 8]) = rBL[1];
    __syncthreads();
    if (it + 1 < NI) load(it + 1);

    #pragma unroll
    for (int ks = 0; ks < 2; ++ks) {
      const int ao = ab + ks * 32, bo = bb + ks * 32;
      short8 ah0 = *reinterpret_cast<const short8*>(&aHs[ao]);
      short8 ah1 = *reinterpret_cast<const short8*>(&aHs[ao + 1152]);
      short8 bh0 = *reinterpret_cast<const short8*>(&bHs[bo]);
      short8 bh1 = *reinterpret_cast<const short8*>(&bHs[bo + 1152]);
      acc[0][0] = __builtin_amdgcn_mfma_f32_16x16x32_bf16(ah0, bh0, acc[0][0], 0, 0, 0);
      acc[0][1] = __builtin_amdgcn_mfma_f32_16x16x32_bf16(ah0, bh1, acc[0][1], 0, 0, 0);
      acc[1][0] = __builtin_amdgcn_mfma_f32_16x16x32_bf16(ah1, bh0, acc[1][0], 0, 0, 0);
      acc[1][1] = __builtin_amdgcn_mfma_f32_16x16x32_bf16(ah1, bh1, acc[1][1], 0, 0, 0);
      short8 al0 = *reinterpret_cast<const short8*>(&aLs[ao]);
      short8 al1 = *reinterpret_cast<const short8*>(&aLs[ao + 1152]);
      acc[0][0] = __builtin_amdgcn_mfma_f32_16x16x32_bf16(al0, bh0, acc[0][0], 0, 0, 0);
      acc[0][1] = __builtin_amdgcn_mfma_f32_16x16x32_bf16(al0, bh1, acc[0][1], 0, 0, 0);
      acc[1][0] = __builtin_amdgcn_mfma_f32_16x16x32_bf16(al1, bh0, acc[1][0], 0, 0, 0);
      acc[1][1] = __builtin_amdgcn_mfma_f32_16x16x32_bf16(al1, bh1, acc[1][1], 0, 0, 0);
      short8 bl0 = *reinterpret_cast<const short8*>(&bLs[bo]);
      short8 bl1 = *reinterpret_cast<const short8*>(&bLs[bo + 1152]);
      acc[0][0] = __builtin_amdgcn_mfma_f32_16x16x32_bf16(ah0, bl0, acc[0][0], 0, 0, 0);
      acc[0][1] = __builtin_amdgcn_mfma_f32_16x16x32_bf16(ah0, bl1, acc[0][1], 0, 0, 0);
      acc[1][0] = __builtin_amdgcn_mfma_f32_16x16x32_bf16(ah1, bl0, acc[1][0], 0, 0, 0);
      acc[1][1] = __builtin_amdgcn_mfma_f32_16x16x32_bf16(ah1, bl1, acc[1][1], 0, 0, 0);
    }
  }

  // Epilogue. C layout: col = lane&15 (n), row = fq*4 + reg (m).
  #pragma unroll
  for (int mt = 0; mt < 2; ++mt) {
    const int mB2 = m0 + wm + mt * 16 + fq * 4;
    #pragma unroll
    for (int nt = 0; nt < 2; ++nt) {
      const int n = n0 + wn + nt * 16 + fr;
      f32x4 c = acc[mt][nt];
      #pragma unroll
      for (int r = 0; r < 4; ++r) {
        const int m = mB2 + r;
        if (m < MROWS) {
          if (EPI == 3) {
            outF[((size_t)blockIdx.z * MP + m) * 512 + n] = c[r];
          } else if (EPI == 2) {
            outF[(size_t)m * NS + n] = c[r];
          } else {
            float x = c[r] + bias[n];
            if (EPI == 1) x = fmaxf(x, 0.f);
            int bb2 = m / TDIV, tt2 = m - bb2 * TDIV;
            int orow = bb2 * OSB + OS0 + tt2;
            unsigned short h = f2bf_rne(x);
            float hf = __uint_as_float((unsigned)h << 16);
            unsigned short l = f2bf_rne(x - hf);
            outH[(size_t)orow * 512 + n] = (short)h;
            outL[(size_t)orow * 512 + n] = (short)l;
          }
        }
      }
    }
  }
}

// ---------------------------------------------------------------------------
// FC GEMM (f32 operands, in-loop split): M=8192 N=512 K=1024, 64x64 tile,
// KCH=32. Epilogue writes hi/lo planes.
// ---------------------------------------------------------------------------
__global__ __launch_bounds__(256) void fc_gemm(
    const float* __restrict__ A, const float* __restrict__ Bw,
    const float* __restrict__ bias,
    short* __restrict__ outH, short* __restrict__ outL) {
  __shared__ short aHs[64 * 40], aLs[64 * 40], bHs[64 * 40], bLs[64 * 40];
  const int tid = threadIdx.x;
  const int m0 = blockIdx.x * 64, n0 = blockIdx.y * 64;
  const int wave = tid >> 6, lane = tid & 63;
  const int wm = (wave >> 1) * 32, wn = (wave & 1) * 32;
  const int fr = lane & 15, fq = lane >> 4;
  const int srow = tid >> 2, seg = tid & 3;

  f32x4 acc[2][2];
  #pragma unroll
  for (int i = 0; i < 2; ++i)
    #pragma unroll
    for (int j = 0; j < 2; ++j) acc[i][j] = (f32x4)0.f;

  float4 ra[2], rb[2];
  auto load = [&](int it) {
    const float* pa = &A[(size_t)(m0 + srow) * 1024 + it * 32 + seg * 8];
    ra[0] = *reinterpret_cast<const float4*>(pa);
    ra[1] = *reinterpret_cast<const float4*>(pa + 4);
    const float* pb2 = &Bw[(size_t)(n0 + srow) * 1024 + it * 32 + seg * 8];
    rb[0] = *reinterpret_cast<const float4*>(pb2);
    rb[1] = *reinterpret_cast<const float4*>(pb2 + 4);
  };
  auto cvt = [&](const float4 r0, const float4 r1, short8& h8, short8& l8) {
    float tf[8];
    *reinterpret_cast<float4*>(tf) = r0;
    *reinterpret_cast<float4*>(tf + 4) = r1;
    #pragma unroll
    for (int j = 0; j < 8; ++j) {
      unsigned short h = f2bf_rne(tf[j]);
      float hf = __uint_as_float((unsigned)h << 16);
      h8[j] = (short)h;
      l8[j] = (short)f2bf_rne(tf[j] - hf);
    }
  };

  load(0);
  const int sb = srow * 40 + seg * 8;
  const int ab = (wm + fr) * 40 + fq * 8;
  const int bb = (wn + fr) * 40 + fq * 8;

  for (int it = 0; it < 32; ++it) {
    __syncthreads();
    short8 h8, l8;
    cvt(ra[0], ra[1], h8, l8);
    *reinterpret_cast<short8*>(&aHs[sb]) = h8;
    *reinterpret_cast<short8*>(&aLs[sb]) = l8;
    cvt(rb[0], rb[1], h8, l8);
    *reinterpret_cast<short8*>(&bHs[sb]) = h8;
    *reinterpret_cast<short8*>(&bLs[sb]) = l8;
    __syncthreads();
    if (it + 1 < 32) load(it + 1);

    short8 ah0 = *reinterpret_cast<const short8*>(&aHs[ab]);
    short8 ah1 = *reinterpret_cast<const short8*>(&aHs[ab + 640]);
    short8 bh0 = *reinterpret_cast<const short8*>(&bHs[bb]);
    short8 bh1 = *reinterpret_cast<const short8*>(&bHs[bb + 640]);
    acc[0][0] = __builtin_amdgcn_mfma_f32_16x16x32_bf16(ah0, bh0, acc[0][0], 0, 0, 0);
    acc[0][1] = __builtin_amdgcn_mfma_f32_16x16x32_bf16(ah0, bh1, acc[0][1], 0, 0, 0);
    acc[1][0] = __builtin_amdgcn_mfma_f32_16x16x32_bf16(ah1, bh0, acc[1][0], 0, 0, 0);
    acc[1][1] = __builtin_amdgcn_mfma_f32_16x16x32_bf16(ah1, bh1, acc[1][1], 0, 0, 0);
    short8 al0 = *reinterpret_cast<const short8*>(&aLs[ab]);
    short8 al1 = *reinterpret_cast<const short8*>(&aLs[ab + 640]);
    acc[0][0] = __builtin_amdgcn_mfma_f32_16x16x32_bf16(al0, bh0, acc[0][0], 0, 0, 0);
    acc[0][1] = __builtin_amdgcn_mfma_f32_16x16x32_bf16(al0, bh1, acc[0][1], 0, 0, 0);
    acc[1][0] = __builtin_amdgcn_mfma_f32_16x16x32_bf16(al1, bh0, acc[1][0], 0, 0, 0);
    acc[1][1] = __builtin_amdgcn_mfma_f32_16x16x32_bf16(al1, bh1, acc[1][1], 0, 0, 0);
    short8 bl0 = *reinterpret_cast<const short8*>(&bLs[bb]);
    short8 bl1 = *reinterpret_cast<const short8*>(&bLs[bb + 640]);
    acc[0][0] = __builtin_amdgcn_mfma_f32_16x16x32_bf16(ah0, bl0, acc[0][0], 0, 0, 0);
    acc[0][1] = __builtin_amdgcn_mfma_f32_16x16x32_bf16(ah0, bl1, acc[0][1], 0, 0, 0);
    acc[1][0] = __builtin_amdgcn_mfma_f32_16x16x32_bf16(ah1, bl0, acc[1][0], 0, 0, 0);
    acc[1][1] = __builtin_amdgcn_mfma_f32_16x16x32_bf16(ah1, bl1, acc[1][1], 0, 0, 0);
  }

  #pragma unroll
  for (int mt = 0; mt < 2; ++mt) {
    const int mB2 = m0 + wm + mt * 16 + fq * 4;
    #pragma unroll
    for (int nt = 0; nt < 2; ++nt) {
      const int n = n0 + wn + nt * 16 + fr;
      f32x4 c = acc[mt][nt];
      #pragma unroll
      for (int r = 0; r < 4; ++r) {
        const int m = mB2 + r;
        float x = c[r] + bias[n];
        unsigned short h = f2bf_rne(x);
        float hf = __uint_as_float((unsigned)h << 16);
        unsigned short l = f2bf_rne(x - hf);
        outH[(size_t)m * 512 + n] = (short)h;
        outL[(size_t)m * 512 + n] = (short)l;
      }
    }
  }
}

// ---------------------------------------------------------------------------
// Split-K reduce: out(orow) = relu(sum_ks partial[ks][m] + bias) -> hi/lo
// ---------------------------------------------------------------------------
__global__ __launch_bounds__(256) void reduce_kernel(
    const float* __restrict__ part, const float* __restrict__ bias,
    short* __restrict__ outH, short* __restrict__ outL,
    int kS, int MROWS, int MP, int Tl, int Poff) {
  int idx = blockIdx.x * 256 + threadIdx.x;
  if (idx >= MROWS * 512) return;
  int m = idx >> 9, n = idx & 511;
  float s = 0.f;
  for (int ks = 0; ks < kS; ++ks) s += part[((size_t)ks * MP + m) * 512 + n];
  float x = fmaxf(s + bias[n], 0.f);
  int b2 = m / Tl, t2 = m - b2 * Tl;
  int orow = b2 * P_ + Poff + t2;
  unsigned short h = f2bf_rne(x);
  float hf = __uint_as_float((unsigned)h << 16);
  unsigned short l = f2bf_rne(x - hf);
  outH[(size_t)orow * 512 + n] = (short)h;
  outL[(size_t)orow * 512 + n] = (short)l;
}

// ---------------------------------------------------------------------------
// Elementwise f32 -> hi/lo bf16 planes (count multiple of 4)
// ---------------------------------------------------------------------------
__global__ __launch_bounds__(256) void split_kernel(
    const float* __restrict__ in, short* __restrict__ oh, short* __restrict__ ol,
    int n4) {
  int i = blockIdx.x * 256 + threadIdx.x;
  if (i >= n4) return;
  float4 v = *reinterpret_cast<const float4*>(&in[(size_t)i * 4]);
  float tf[4] = {v.x, v.y, v.z, v.w};
  short4v h4, l4;
  #pragma unroll
  for (int j = 0; j < 4; ++j) {
    unsigned short h = f2bf_rne(tf[j]);
    float hf = __uint_as_float((unsigned)h << 16);
    h4[j] = (short)h;
    l4[j] = (short)f2bf_rne(tf[j] - hf);
  }
  *reinterpret_cast<short4v*>(&oh[(size_t)i * 4]) = h4;
  *reinterpret_cast<short4v*>(&ol[(size_t)i * 4]) = l4;
}

// ---------------------------------------------------------------------------
// Repack+split conv weights: [li][o][i][k] -> planes [li*512+o][k*512+i]
// ---------------------------------------------------------------------------
__global__ __launch_bounds__(256) void repack_kernel(
    const float* __restrict__ w, short* __restrict__ oh, short* __restrict__ ol) {
  int e = blockIdx.x * 256 + threadIdx.x;
  if (e >= 6 * 512 * 512) return;
  float4 v = *reinterpret_cast<const float4*>(&w[(size_t)e * 4]);
  float tf[4] = {v.x, v.y, v.z, v.w};
  int li = e >> 18, rem = e & 262143, o = rem >> 9, i = rem & 511;
  size_t rb = ((size_t)(li * 512 + o)) * 2048 + i;
  #pragma unroll
  for (int k = 0; k < 4; ++k) {
    unsigned short h = f2bf_rne(tf[k]);
    float hf = __uint_as_float((unsigned)h << 16);
    oh[rb + k * 512] = (short)h;
    ol[rb + k * 512] = (short)f2bf_rne(tf[k] - hf);
  }
}

// ---------------------------------------------------------------------------
// Row L2 norms of f_all planes
// ---------------------------------------------------------------------------
__global__ __launch_bounds__(256) void fnorm_kernel(
    const short* __restrict__ fH, const short* __restrict__ fL,
    float* __restrict__ fn) {
  int gw = (blockIdx.x * 256 + threadIdx.x) >> 6;
  int lane = threadIdx.x & 63;
  if (gw >= B_ * P_) return;
  short8 h = *reinterpret_cast<const short8*>(&fH[(size_t)gw * 512 + lane * 8]);
  short8 l = *reinterpret_cast<const short8*>(&fL[(size_t)gw * 512 + lane * 8]);
  float s = 0.f;
  #pragma unroll
  for (int j = 0; j < 8; ++j) {
    float x = bf2f(h[j]) + bf2f(l[j]);
    s += x * x;
  }
  #pragma unroll
  for (int off = 32; off; off >>= 1) s += __shfl_xor(s, off);
  if (lane == 0) fn[gw] = sqrtf(s);
}

// ---------------------------------------------------------------------------
// Per-query word Gram matrices
// ---------------------------------------------------------------------------
__global__ __launch_bounds__(256) void gram_kernel(
    const float* __restrict__ words, float* __restrict__ gram) {
  __shared__ float wsh[L_][513];
  int q = blockIdx.x, tid = threadIdx.x;
  for (int idx = tid; idx < L_ * 512; idx += 256)
    wsh[idx >> 9][idx & 511] = words[(size_t)q * L_ * J_ + idx];
  __syncthreads();
  for (int pr = tid; pr < L_ * L_; pr += 256) {
    int l = pr / L_, l2 = pr % L_;
    float sum = 0.f;
    for (int d = 0; d < J_; ++d) sum += wsh[l][d] * wsh[l2][d];
    gram[q * L_ * L_ + pr] = sum;
  }
}

// ---------------------------------------------------------------------------
// Softmax + cosine-sim epilogue per (q,b,p).
// ---------------------------------------------------------------------------
__global__ __launch_bounds__(256) void sim_kernel(
    const float* __restrict__ logits, const float* __restrict__ gram,
    const float* __restrict__ fnorm, float* __restrict__ score) {
  int idx = blockIdx.x * 256 + threadIdx.x;
  if (idx >= Q_ * B_ * P_) return;
  int q = idx / (B_ * P_);
  int r = idx - q * (B_ * P_);
  const float* lg = &logits[(size_t)r * (Q_ * L_) + q * L_];
  float raw[L_], e[L_];
  float m = -1e30f;
  #pragma unroll
  for (int l = 0; l < L_; ++l) { raw[l] = lg[l]; m = fmaxf(m, raw[l]); }
  float s = 0.f;
  #pragma unroll
  for (int l = 0; l < L_; ++l) { e[l] = __expf(raw[l] - m); s += e[l]; }
  float inv = 1.f / s;
  float fvs = 0.f;
  #pragma unroll
  for (int l = 0; l < L_; ++l) fvs += e[l] * raw[l];
  fvs *= inv;
  const float* G = &gram[q * L_ * L_];
  float vn2 = 0.f;
  for (int l = 0; l < L_; ++l) {
    float acc = 0.f;
    #pragma unroll
    for (int l2 = 0; l2 < L_; ++l2) acc += e[l2] * G[l * L_ + l2];
    vn2 += e[l] * acc;
  }
  vn2 *= inv * inv;
  float fn = fnorm[r] + 1e-8f;
  float vn = sqrtf(fmaxf(vn2, 0.f)) + 1e-8f;
  score[idx] = fvs / (fn * vn);
}

// ---------------------------------------------------------------------------
// Greedy NMS
// ---------------------------------------------------------------------------
__global__ __launch_bounds__(256) void nms_kernel(
    const float* __restrict__ score, const float* __restrict__ iou,
    const float* __restrict__ lam, float* __restrict__ smat) {
  int wid = (blockIdx.x * 256 + threadIdx.x) >> 6;
  int lane = threadIdx.x & 63;
  if (wid >= Q_ * B_) return;
  const float* srow = &score[(size_t)wid * P_];
  float s[4];
  #pragma unroll
  for (int i = 0; i < 4; ++i) {
    int p = lane + 64 * i;
    s[i] = (p < P_) ? srow[p] : NEG_;
  }
  float lamv = lam[0];
  float acc = 0.f, wgt = 1.f;
  for (int k = 0; k < 5; ++k) {
    float bv = NEG_ * 2.f; int bi = 1 << 30;
    #pragma unroll
    for (int i = 0; i < 4; ++i) {
      int p = lane + 64 * i;
      if (s[i] > bv) { bv = s[i]; bi = p; }
    }
    for (int off = 32; off; off >>= 1) {
      float ov = __shfl_xor(bv, off);
      int oi = __shfl_xor(bi, off);
      if (ov > bv || (ov == bv && oi < bi)) { bv = ov; bi = oi; }
    }
    acc += bv * wgt;
    wgt *= lamv;
    const float* irow = &iou[(size_t)bi * P_];
    #pragma unroll
    for (int i = 0; i < 4; ++i) {
      int p = lane + 64 * i;
      if (p < P_ && irow[p] > 0.7f) s[i] = NEG_;
      if (p == bi) s[i] = NEG_;
    }
  }
  if (lane == 0) smat[wid] = acc * 0.2f;
}

// ---------------------------------------------------------------------------
// positive_map
// ---------------------------------------------------------------------------
__global__ __launch_bounds__(256) void posmap_kernel(
    const float* __restrict__ score, float* __restrict__ out) {
  int idx = blockIdx.x * 256 + threadIdx.x;
  if (idx >= B_ * P_) return;
  int b = idx / P_, p = idx - b * P_;
  out[1 + idx] = score[((size_t)(b * B_ + b)) * P_ + p];
}

// ---------------------------------------------------------------------------
// diag margin loss
// ---------------------------------------------------------------------------
__global__ __launch_bounds__(1024) void loss_kernel(
    const float* __restrict__ smat, float* __restrict__ out) {
  __shared__ float sm[B_][B_ + 1];
  __shared__ float red[16];
  int tid = threadIdx.x;
  sm[tid >> 5][tid & 31] = smat[tid];
  __syncthreads();
  int i = tid >> 5, j = tid & 31;
  float val = 0.f;
  if (i != j) {
    float sij = sm[i][j];
    val = fmaxf(0.f, 0.2f + sij - sm[i][i]) + fmaxf(0.f, 0.2f + sij - sm[j][j]);
  }
  #pragma unroll
  for (int off = 32; off; off >>= 1) val += __shfl_xor(val, off);
  if ((tid & 63) == 0) red[tid >> 6] = val;
  __syncthreads();
  if (tid == 0) {
    float t = 0.f;
    #pragma unroll
    for (int w = 0; w < 16; ++w) t += red[w];
    out[0] = t / 32.f;
  }
}

extern "C" void kernel_launch(void* const* d_in, const int* in_sizes, int n_in,
                              void* d_out, int out_size, void* d_ws, size_t ws_size,
                              hipStream_t stream) {
  const float* video  = (const float*)d_in[0];
  const float* words  = (const float*)d_in[1];
  // d_in[2] = w_masks: all-ones by construction, unused
  const float* lam    = (const float*)d_in[3];
  const float* iou    = (const float*)d_in[4];
  const float* fc_w   = (const float*)d_in[5];
  const float* fc_b   = (const float*)d_in[6];
  const float* conv_w = (const float*)d_in[7];
  const float* conv_b = (const float*)d_in[8];
  const float* pw     = (const float*)d_in[9];
  const float* pb     = (const float*)d_in[10];
  float* out = (float*)d_out;

  // Workspace layout (byte offsets). Stream-order aliasing:
  //   region A [0, 16.77 MB): fc_out planes -> (conv1+) partials -> f_all planes
  //   region B [16.77, 41.94): conv weight planes -> logits f32
  char* base = (char*)d_ws;
  short* fcoH  = (short*)(base + 0);                    // 8192*512 shorts
  short* fcoL  = (short*)(base + 8388608);
  float* part  = (float*)(base + 0);                    // alias, max 8.1 MB
  short* fallH = (short*)(base + 0);                    // alias, 7712*512
  short* fallL = (short*)(base + 7897088);
  short* cwH   = (short*)(base + 16777216);             // 6*512*2048 shorts
  short* cwL   = (short*)(base + 16777216 + 12582912);
  float* logits= (float*)(base + 16777216);             // alias, 19.7 MB
  short* pyrH  = (short*)(base + 41943040);             // 7712*512 shorts
  short* pyrL  = (short*)(base + 41943040 + 7897088);
  short* pwH   = (short*)(base + 57737216);
  short* pwL   = (short*)(base + 58261504);
  short* wordsH= (short*)(base + 58785792);
  short* wordsL= (short*)(base + 59441152);
  float* score = (float*)(base + 60096512);
  float* fnorm = score + 246784;
  float* gram  = fnorm + 7936;
  float* smat  = gram + 12800;

  const int Tl[6]   = {127, 62, 30, 14, 6, 2};
  const int Poff[6] = {0, 127, 189, 219, 233, 239};

  // 0) operand prep: conv weights repack+split, pw/words split
  repack_kernel<<<6144, 256, 0, stream>>>(conv_w, cwH, cwL);
  split_kernel<<<256, 256, 0, stream>>>(pw, pwH, pwL, 65536);
  split_kernel<<<320, 256, 0, stream>>>(words, wordsH, wordsL, 81920);

  // 1) FC: M=8192 N=512 K=1024 -> fc_out hi/lo planes
  fc_gemm<<<dim3(128, 8), 256, 0, stream>>>(video, fc_w, fc_b, fcoH, fcoL);

  // 2) conv0 (no split-K): M=4064, K=2048, im2col over fc_out planes
  gemm_bf<1><<<dim3(64, 8, 1), 256, 0, stream>>>(
      fcoH, fcoL, cwH, cwL, conv_b, pyrH, pyrL, nullptr,
      4064, 127, 256, 0, 2, 2048, 2048, 0, P_, 0, 512);

  // 3) conv1..5: split-K partials + reduce
  const int Ms[5]    = {1984, 960, 448, 192, 64};
  const int kSs[5]   = {2, 2, 4, 4, 8};
  const int KLENs[5] = {1024, 1024, 512, 512, 256};
  for (int i = 0; i < 5; ++i) {
    int li = i + 1;
    gemm_bf<3><<<dim3(Ms[i] / 64, 8, kSs[i]), 256, 0, stream>>>(
        pyrH, pyrL, cwH + (size_t)li * 512 * 2048, cwL + (size_t)li * 512 * 2048,
        nullptr, nullptr, nullptr, part,
        Ms[i], Tl[li], P_, Poff[li - 1], 2, 2048, KLENs[i], Ms[i], 0, 0, 512);
    reduce_kernel<<<Ms[i] * 2, 256, 0, stream>>>(
        part, conv_b + li * 512, pyrH, pyrL, kSs[i], Ms[i], Ms[i], Tl[li], Poff[li]);
  }

  // 4) pointwise projection (all layers): M=7712 N=512 K=512 -> f_all planes
  gemm_bf<0><<<dim3(121, 8, 1), 256, 0, stream>>>(
      pyrH, pyrL, pwH, pwL, pb, fallH, fallL, nullptr,
      B_ * P_, B_ * P_, 0, 0, 1, 512, 512, 0, 1, 0, 512);

  // 5) norms, Gram, attention logits (M=7712 N=640 K=512, f32 out)
  fnorm_kernel<<<1928, 256, 0, stream>>>(fallH, fallL, fnorm);
  gram_kernel<<<Q_, 256, 0, stream>>>(words, gram);
  gemm_bf<2><<<dim3(121, 10, 1), 256, 0, stream>>>(
      fallH, fallL, wordsH, wordsL, nullptr, nullptr, nullptr, logits,
      B_ * P_, B_ * P_, 0, 0, 1, 512, 512, 0, 0, 0, 640);

  // 6) softmax + cosine similarity
  sim_kernel<<<964, 256, 0, stream>>>(logits, gram, fnorm, score);

  // 7) NMS, positive_map, loss
  nms_kernel<<<256, 256, 0, stream>>>(score, iou, lam, smat);
  posmap_kernel<<<31, 256, 0, stream>>>(score, out);
  loss_kernel<<<1, 1024, 0, stream>>>(smat, out);
}